// Round 10
// baseline (75.087 us; speedup 1.0000x reference)
//
#include <hip/hip_runtime.h>

namespace {

constexpr int F_FEAT = 310;
constexpr int KDIM   = 309;
constexpr int BSZ    = 2048;
constexpr int HDIM   = 32;
constexpr int NCH    = 10;          // K chunks of 32 (309 -> 320, zero-padded in W1T)
constexpr int NX     = F_FEAT * BSZ;

// workspace layout
constexpr int    NBLK8    = NX / 8 + 2;               // 79362 16B blocks per x copy
constexpr size_t CSTR_B   = (size_t)NBLK8 * 16;       // bytes per x copy
constexpr size_t XC_BYTES = CSTR_B * 8;               // 8 shift copies
constexpr size_t W1T_FSTR = 32 * 320 * 2;             // [32 h][320 k] bf16 (pre-swizzled)
constexpr size_t W1T_OFF  = XC_BYTES;
constexpr size_t W2T_OFF  = W1T_OFF + (size_t)F_FEAT * W1T_FSTR;
constexpr size_t WT_FSTR  = 32 * 32 * 2;
constexpr size_t W3T_OFF  = W2T_OFF + (size_t)F_FEAT * WT_FSTR;
constexpr size_t WS_NEED  = W3T_OFF + (size_t)F_FEAT * WT_FSTR;

constexpr int NBX      = (NBLK8 + 255) / 256;         // 311 blocks per copy
constexpr int CVT_XBLK = NBX * 8;                     // 2488 x-role blocks
constexpr int CVT_BLK  = CVT_XBLK + F_FEAT * 6;       // + 1860 w-role blocks

typedef __bf16 bf16x8 __attribute__((ext_vector_type(8)));
typedef float  f32x4  __attribute__((ext_vector_type(4)));
typedef int    i32x4  __attribute__((ext_vector_type(4)));

#define MFMA(a, b, c) __builtin_amdgcn_mfma_f32_16x16x32_bf16((a), (b), (c), 0, 0, 0)

// ---------- one fused conversion pass (unchanged, proven) ----------
__global__ __launch_bounds__(256) void cvt_all(
    const float* __restrict__ x,  const float* __restrict__ W1,
    const float* __restrict__ W2, const float* __restrict__ W3,
    char* __restrict__ ws)
{
    __shared__ float tile[64][33];
    const int b = blockIdx.x, tid = threadIdx.x;

    if (b < CVT_XBLK) {
        const int c = b / NBX, mb = b - c * NBX;
        const int m = mb * 256 + tid;
        if (m >= NBLK8) return;
        const int e0 = m * 8 - c;
        bf16x8 v;
        #pragma unroll
        for (int q = 0; q < 8; ++q) {
            const int i = e0 + q;
            v[q] = (__bf16)((i >= 0 && i < NX) ? x[i] : 0.f);
        }
        *(bf16x8*)(ws + (size_t)c * CSTR_B + (size_t)m * 16) = v;
        return;
    }

    const int wb = b - CVT_XBLK;
    const int fi = wb / 6, part = wb - fi * 6;

    if (part < 5) {   // W1 chunk-pair: 64k x 32h transpose (2048 elems = 256 thr x 8)
        const float* Wg = W1 + (size_t)fi * KDIM * HDIM;
        const int row = tid >> 2;
        const int c8  = (tid & 3) * 8;
        const int k   = part * 64 + row;
        float4 f0 = make_float4(0,0,0,0), f1 = f0;
        if (k < KDIM) {
            f0 = *(const float4*)&Wg[k * HDIM + c8];
            f1 = *(const float4*)&Wg[k * HDIM + c8 + 4];
        }
        tile[row][c8+0] = f0.x; tile[row][c8+1] = f0.y;
        tile[row][c8+2] = f0.z; tile[row][c8+3] = f0.w;
        tile[row][c8+4] = f1.x; tile[row][c8+5] = f1.y;
        tile[row][c8+6] = f1.z; tile[row][c8+7] = f1.w;
        __syncthreads();
        const int h = tid & 31, kq = (tid >> 5) * 8;
        bf16x8 o;
        #pragma unroll
        for (int j = 0; j < 8; ++j) o[j] = (__bf16)tile[kq + j][h];
        const int boff = (h * 640 + part * 128 + kq * 2) ^ ((h & 7) << 4);
        *(bf16x8*)(ws + W1T_OFF + (size_t)fi * W1T_FSTR + (size_t)boff) = o;
    } else {          // W2 & W3: 32x32 transpose each (1024 elems = 128 thr x 8)
        const int kl = tid >> 3, h4 = (tid & 7) * 4;
        const int h = tid & 31, kq = (tid >> 5) * 8;
        {
            const float* Wg = W2 + (size_t)fi * HDIM * HDIM;
            float4 f = *(const float4*)&Wg[kl * HDIM + h4];
            tile[kl][h4+0] = f.x; tile[kl][h4+1] = f.y;
            tile[kl][h4+2] = f.z; tile[kl][h4+3] = f.w;
            __syncthreads();
            if (tid < 128) {
                bf16x8 o;
                #pragma unroll
                for (int j = 0; j < 8; ++j) o[j] = (__bf16)tile[kq + j][h];
                *(bf16x8*)(ws + W2T_OFF + (size_t)fi * WT_FSTR + (size_t)(h * 32 + kq) * 2) = o;
            }
            __syncthreads();
        }
        {
            const float* Wg = W3 + (size_t)fi * HDIM * HDIM;
            float4 f = *(const float4*)&Wg[kl * HDIM + h4];
            tile[kl][h4+0] = f.x; tile[kl][h4+1] = f.y;
            tile[kl][h4+2] = f.z; tile[kl][h4+3] = f.w;
            __syncthreads();
            if (tid < 128) {
                bf16x8 o;
                #pragma unroll
                for (int j = 0; j < 8; ++j) o[j] = (__bf16)tile[kq + j][h];
                *(bf16x8*)(ws + W3T_OFF + (size_t)fi * WT_FSTR + (size_t)(h * 32 + kq) * 2) = o;
            }
        }
    }
}

// ---------- fused per-feature MLP: asm-forced counted-vmcnt pipeline, sb-major XCD ----------
template<bool FAST>
__global__ __launch_bounds__(256, 4) void sfp6(
    const float* __restrict__ x,
    const float* __restrict__ W1, const float* __restrict__ b1,
    const float* __restrict__ W2, const float* __restrict__ b2,
    const float* __restrict__ W3, const float* __restrict__ b3,
    const char* __restrict__ ws, float* __restrict__ out)
{
    __shared__ __attribute__((aligned(16))) __bf16 W1s[32 * 320];   // 20480 B
    __shared__ __attribute__((aligned(16))) __bf16 h1s[256 * 40];   // 20480 B

    // sb-major: XCD = blk&7 = sample block -> x-window L2-resident across features
    const int fi = blockIdx.x >> 3, sb = blockIdx.x & 7;

    const int tid = threadIdx.x, lane = tid & 63, wv = tid >> 6;
    const int l15 = lane & 15, l16 = lane >> 4;
    const int lk8 = l16 * 8, r0 = l16 * 4;
    const int b0 = sb << 8, iB = fi << 11;
    const int mrow = wv * 64;                 // wave owns 64 sample rows, 4 streams of 16

    // per-stream addressing (copy index constant per row since 2048 % 8 == 0)
    int d[4];            // iB - lin[m]
    unsigned off[4];     // byte offset of aligned fragment base within ws
    #pragma unroll
    for (int m = 0; m < 4; ++m) {
        const int lin = (b0 + mrow + 16 * m + l15) * KDIM + lk8;
        d[m] = iB - lin;
        const int c8 = (-lin) & 7;
        off[m] = (unsigned)((size_t)c8 * CSTR_B) + (unsigned)(lin + c8) * 2u;
    }

    auto fragW1 = [&](int c, int hrow) -> bf16x8 {
        if (FAST) {
            const int boff = (hrow * 640 + c * 64 + l16 * 16) ^ ((hrow & 7) << 4);
            return *(const bf16x8*)((const char*)W1s + boff);
        } else {
            const float* Wg = W1 + (size_t)fi * KDIM * HDIM;
            bf16x8 r;
            #pragma unroll
            for (int q = 0; q < 8; ++q) {
                const int k = c * 32 + lk8 + q;
                r[q] = (__bf16)((k < KDIM) ? Wg[k * HDIM + hrow] : 0.f);
            }
            return r;
        }
    };

    f32x4 acc[4][2];
    #pragma unroll
    for (int m = 0; m < 4; ++m) { acc[m][0] = {0,0,0,0}; acc[m][1] = {0,0,0,0}; }

    if constexpr (FAST) {
        // ---- stage W1T (compiler-managed loads), barrier fully drains vmcnt ----
        {
            const char* src = ws + W1T_OFF + (size_t)fi * W1T_FSTR;
            #pragma unroll
            for (int i = 0; i < 5; ++i) {
                const int o = i * 4096 + tid * 16;
                *(bf16x8*)((char*)W1s + o) = *(const bf16x8*)(src + o);
            }
        }
        __syncthreads();   // after this, vmcnt outstanding == 0; loop VMEM is asm-only

        bf16x8 ab[3][4];   // rotating in-flight banks (static idx after unroll)

        auto issueLd = [&](int c) {
            #pragma unroll
            for (int m = 0; m < 4; ++m) {
                const unsigned sel = (32 * c >= d[m]) ? 4096u : 0u;   // LOO skip
                const char* p = ws + (off[m] + (unsigned)(64 * c) + sel);
                i32x4 r;
                asm volatile("global_load_dwordx4 %0, %1, off" : "=v"(r) : "v"(p));
                ab[c % 3][m] = __builtin_bit_cast(bf16x8, r);
            }
        };

        issueLd(0);
        issueLd(1);

        #pragma unroll
        for (int c = 0; c < NCH; ++c) {
            if (c + 2 < NCH) issueLd(c + 2);                  // 12 outstanding max
            bf16x8 w0 = fragW1(c, l15), w1 = fragW1(c, 16 + l15);  // ds_read, lgkm
            if (c <= 7)      asm volatile("s_waitcnt vmcnt(8)");   // chunk c landed
            else if (c == 8) asm volatile("s_waitcnt vmcnt(4)");
            else             asm volatile("s_waitcnt vmcnt(0)");
            __builtin_amdgcn_sched_barrier(0);                // rule #18 fence

            // rare straddle patch (<=1 lane per feature across the whole grid)
            const bool h0 = (unsigned)(d[0] - 32*c - 1) < 7u;
            const bool h1 = (unsigned)(d[1] - 32*c - 1) < 7u;
            const bool h2 = (unsigned)(d[2] - 32*c - 1) < 7u;
            const bool h3 = (unsigned)(d[3] - 32*c - 1) < 7u;
            if (__any(h0 | h1 | h2 | h3)) {
                #pragma unroll
                for (int m = 0; m < 4; ++m) {
                    const bool hm = (unsigned)(d[m] - 32*c - 1) < 7u;
                    if (hm) {
                        const int li_ = iB - d[m] + 32*c;
                        bf16x8 r;
                        #pragma unroll
                        for (int q = 0; q < 8; ++q) {
                            int i = li_ + q; i += (i >= iB) ? BSZ : 0;
                            r[q] = *(const __bf16*)(ws + (size_t)i * 2);   // copy 0
                        }
                        ab[c % 3][m] = r;
                    }
                }
            }

            #pragma unroll
            for (int m = 0; m < 4; ++m) {
                acc[m][0] = MFMA(ab[c % 3][m], w0, acc[m][0]);
                acc[m][1] = MFMA(ab[c % 3][m], w1, acc[m][1]);
            }
        }
        __builtin_amdgcn_sched_barrier(0);   // keep epilogue loads below the counted region
    } else {
        // safe fallback: compiler-managed loads from raw fp32 x
        auto fragA = [&](int li_) -> bf16x8 {
            bf16x8 r;
            #pragma unroll
            for (int q = 0; q < 8; ++q) {
                int i = li_ + q; i += (i >= iB) ? BSZ : 0;
                i = (i < NX) ? i : (NX - 1);
                r[q] = (__bf16)x[i];
            }
            return r;
        };
        for (int c = 0; c < NCH; ++c) {
            bf16x8 w0 = fragW1(c, l15), w1 = fragW1(c, 16 + l15);
            #pragma unroll
            for (int m = 0; m < 4; ++m) {
                bf16x8 a = fragA(iB - d[m] + 32 * c);
                acc[m][0] = MFMA(a, w0, acc[m][0]);
                acc[m][1] = MFMA(a, w1, acc[m][1]);
            }
        }
    }

    // ---- de-hoisted W2/W3 fragments + biases (latency overlaps epilogue) ----
    bf16x8 w2a, w2b, w3a, w3b;
    if (FAST) {
        const char* p2 = ws + W2T_OFF + (size_t)fi * WT_FSTR;
        const char* p3 = ws + W3T_OFF + (size_t)fi * WT_FSTR;
        w2a = *(const bf16x8*)(p2 + (size_t)(l15 * 32 + lk8) * 2);
        w2b = *(const bf16x8*)(p2 + (size_t)((16 + l15) * 32 + lk8) * 2);
        w3a = *(const bf16x8*)(p3 + (size_t)(l15 * 32 + lk8) * 2);
        w3b = *(const bf16x8*)(p3 + (size_t)((16 + l15) * 32 + lk8) * 2);
    } else {
        #pragma unroll
        for (int q = 0; q < 8; ++q) {
            const size_t base2 = (size_t)fi * HDIM * HDIM + (lk8 + q) * HDIM;
            w2a[q] = (__bf16)W2[base2 + l15];      w2b[q] = (__bf16)W2[base2 + 16 + l15];
            w3a[q] = (__bf16)W3[base2 + l15];      w3b[q] = (__bf16)W3[base2 + 16 + l15];
        }
    }
    const float b1v0 = b1[fi*HDIM + l15], b1v1 = b1[fi*HDIM + 16 + l15];
    const float b2v0 = b2[fi*HDIM + l15], b2v1 = b2[fi*HDIM + 16 + l15];
    const float b3v0 = b3[fi*HDIM + l15], b3v1 = b3[fi*HDIM + 16 + l15];

    // ---- bias+relu -> h1 (wave-local LDS transpose, no barrier) ----
    constexpr int LDA = 40;
    #pragma unroll
    for (int m = 0; m < 4; ++m)
        #pragma unroll
        for (int r = 0; r < 4; ++r) {
            float v;
            v = acc[m][0][r] + b1v0; h1s[(mrow + 16*m + r0 + r)*LDA +      l15] = (__bf16)(v > 0.f ? v : 0.f);
            v = acc[m][1][r] + b1v1; h1s[(mrow + 16*m + r0 + r)*LDA + 16 + l15] = (__bf16)(v > 0.f ? v : 0.f);
        }

    // ---------------- layer 2 ----------------
    const f32x4 z = {0,0,0,0};
    f32x4 c2[4][2];
    #pragma unroll
    for (int m = 0; m < 4; ++m) {
        bf16x8 ha = *(const bf16x8*)&h1s[(mrow + 16*m + l15)*LDA + lk8];
        c2[m][0] = MFMA(ha, w2a, z);
        c2[m][1] = MFMA(ha, w2b, z);
    }
    #pragma unroll
    for (int m = 0; m < 4; ++m)
        #pragma unroll
        for (int r = 0; r < 4; ++r) {
            float v;
            v = c2[m][0][r] + b2v0; h1s[(mrow + 16*m + r0 + r)*LDA +      l15] = (__bf16)(v > 0.f ? v : 0.f);
            v = c2[m][1][r] + b2v1; h1s[(mrow + 16*m + r0 + r)*LDA + 16 + l15] = (__bf16)(v > 0.f ? v : 0.f);
        }

    // ---------------- layer 3 + output ----------------
    const size_t orow = (size_t)(fi * BSZ + b0 + mrow);
    #pragma unroll
    for (int m = 0; m < 4; ++m) {
        bf16x8 ha = *(const bf16x8*)&h1s[(mrow + 16*m + l15)*LDA + lk8];
        f32x4 c30 = MFMA(ha, w3a, z);
        f32x4 c31 = MFMA(ha, w3b, z);
        #pragma unroll
        for (int r = 0; r < 4; ++r) {
            float v;
            v = c30[r] + b3v0; out[(orow + 16*m + r0 + r)*HDIM +      l15] = v > 0.f ? v : 0.f;
            v = c31[r] + b3v1; out[(orow + 16*m + r0 + r)*HDIM + 16 + l15] = v > 0.f ? v : 0.f;
        }
    }
}

} // namespace

extern "C" void kernel_launch(void* const* d_in, const int* in_sizes, int n_in,
                              void* d_out, int out_size, void* d_ws, size_t ws_size,
                              hipStream_t stream) {
    const float* x  = (const float*)d_in[0];
    const float* W1 = (const float*)d_in[1];
    const float* b1 = (const float*)d_in[2];
    const float* W2 = (const float*)d_in[3];
    const float* b2 = (const float*)d_in[4];
    const float* W3 = (const float*)d_in[5];
    const float* b3 = (const float*)d_in[6];
    float* out = (float*)d_out;
    char* ws = (char*)d_ws;

    const bool fast = (ws != nullptr) && (ws_size >= WS_NEED);
    if (fast) {
        hipLaunchKernelGGL(cvt_all, dim3(CVT_BLK), dim3(256), 0, stream, x, W1, W2, W3, ws);
        hipLaunchKernelGGL((sfp6<true>), dim3(F_FEAT * 8), dim3(256), 0, stream,
                           x, W1, b1, W2, b2, W3, b3, ws, out);
    } else {
        hipLaunchKernelGGL((sfp6<false>), dim3(F_FEAT * 8), dim3(256), 0, stream,
                           x, W1, b1, W2, b2, W3, b3, ws, out);
    }
}